// Round 3
// baseline (695.644 us; speedup 1.0000x reference)
//
#include <hip/hip_runtime.h>
#include <math.h>

// B=128, E=8, D=512, H=2048. 64 (a,e) pairs.
// v3: barrier-free streaming GEMMs.
//  - NO LDS, NO __syncthreads in GEMM hot loops: each wave is an independent
//    streaming dot-product engine (the 1-GiB fill proves dependency-free
//    waves hit 6.7 TB/s; our GEMMs were at ~2 TB/s with barrier convoys).
//  - W fragments (8 consecutive k per lane, fixed col) loaded DIRECT from
//    global as k-strided scalar loads: 16 consecutive cols/lq-group -> four
//    fully-consumed 64-B segments per instruction, every W byte read once.
//  - A operands are bf16 dwordx4 loads: feat pre-converted once by k_prep
//    (1 MB), hbuf already bf16. Zero A-conversion VALU in the loops.
//  - Blocks = 4 co-located waves (2 m-halves x 2 n-subtiles) sharing W/A
//    lines via L1/L2 (keeps HBM at the 268 MB/GEMM floor).
//  - Register double-buffer depth-1 per wave; TLP (8-16 desync'd waves/CU)
//    supplies outstanding-request depth.

typedef float floatx4 __attribute__((ext_vector_type(4)));
typedef __bf16 bf16x8 __attribute__((ext_vector_type(8)));
typedef unsigned short ushortx8 __attribute__((ext_vector_type(8)));
typedef unsigned short ushortx4 __attribute__((ext_vector_type(4)));

__device__ __forceinline__ unsigned short f2bf(float f) {
    unsigned u = __builtin_bit_cast(unsigned, f);
    u += 0x7fffu + ((u >> 16) & 1u);   // RNE
    return (unsigned short)(u >> 16);
}

// ---------------------------------------------------------------- prep
// feat f32 [128][8][512] -> bf16 (same linear layout). 0.5 M elems.
__global__ __launch_bounds__(256) void k_prep(
    const float* __restrict__ feat, unsigned short* __restrict__ featbf)
{
    const int idx = (blockIdx.x * 256 + threadIdx.x) * 4;
    floatx4 v = *(const floatx4*)(feat + idx);
    ushortx4 o = { f2bf(v[0]), f2bf(v[1]), f2bf(v[2]), f2bf(v[3]) };
    *(ushortx4*)(featbf + idx) = o;
}

// ---------------------------------------------------------------- pass 1
// 2048 blocks: 64 pairs x 32 n-blocks of 64 over H=2048.
// Wave tile 64m x 32n (acc 4x2). No LDS, no barriers.
__global__ __launch_bounds__(256, 3) void k_gemm1(
    const unsigned short* __restrict__ featbf, const float* __restrict__ W1,
    const float* __restrict__ b1, unsigned short* __restrict__ hbuf)
{
    const int bi = blockIdx.x;
    const int xcd = bi & 7, slot = bi >> 3;       // slot 0..255
    const int pair = xcd * 8 + (slot >> 5);       // 8 pairs of one 'a' per XCD
    const int nb = slot & 31;                     // 32 n-blocks of 64
    const int a = pair >> 3;
    const int t = threadIdx.x;
    const int w = t >> 6, l = t & 63;
    const int lr = l & 15, lq = l >> 4;
    const int mh = w & 1, ns = w >> 1;            // m-half, n-subtile
    const int n_base = nb * 64 + ns * 32;

    // W frag element (col, k): W1[pair][k][col], col = n_base + 16j + lr
    const float* W1p = W1 + (size_t)pair * (512 * 2048) + n_base + lr;
    // A frag row mh*64 + 16i + lr, k = kt*32 + lq*8 (bf16, dwordx4-aligned)
    const unsigned short* Ap =
        featbf + ((size_t)(mh * 64 + lr) * 8 + a) * 512 + lq * 8;

    ushortx8 a0[4], a1[4];
    float w0[2][8], w1[2][8];

#define LDA1(KT, S)                                                            \
    {                                                                          \
        _Pragma("unroll")                                                      \
        for (int i = 0; i < 4; ++i)                                            \
            S[i] = *(const ushortx8*)(Ap + (size_t)i * 65536 + (KT) * 32);     \
    }
#define LDW1(KT, S)                                                            \
    {                                                                          \
        _Pragma("unroll")                                                      \
        for (int j = 0; j < 2; ++j)                                            \
            _Pragma("unroll")                                                  \
            for (int jj = 0; jj < 8; ++jj)                                     \
                S[j][jj] = __builtin_nontemporal_load(                         \
                    W1p + 16 * j + (size_t)((KT) * 32 + lq * 8 + jj) * 2048);  \
    }
#define CM1(WS, AS)                                                            \
    {                                                                          \
        bf16x8 wf[2];                                                          \
        _Pragma("unroll")                                                      \
        for (int j = 0; j < 2; ++j) {                                          \
            ushortx8 v;                                                        \
            _Pragma("unroll")                                                  \
            for (int e = 0; e < 8; ++e) v[e] = f2bf(WS[j][e]);                 \
            wf[j] = __builtin_bit_cast(bf16x8, v);                             \
        }                                                                      \
        __builtin_amdgcn_s_setprio(1);                                         \
        _Pragma("unroll")                                                      \
        for (int i = 0; i < 4; ++i)                                            \
            _Pragma("unroll")                                                  \
            for (int j = 0; j < 2; ++j)                                        \
                acc[i][j] = __builtin_amdgcn_mfma_f32_16x16x32_bf16(           \
                    __builtin_bit_cast(bf16x8, AS[i]), wf[j], acc[i][j],       \
                    0, 0, 0);                                                  \
        __builtin_amdgcn_s_setprio(0);                                         \
    }

    floatx4 acc[4][2];
    const floatx4 zero = {0.f, 0.f, 0.f, 0.f};
    #pragma unroll
    for (int i = 0; i < 4; ++i)
        #pragma unroll
        for (int j = 0; j < 2; ++j) acc[i][j] = zero;

    LDW1(0, w0) LDA1(0, a0)
    #pragma unroll 1
    for (int kt = 0; kt < 16; kt += 2) {
        LDW1(kt + 1, w1) LDA1(kt + 1, a1)
        CM1(w0, a0)
        if (kt + 2 < 16) { LDW1(kt + 2, w0) LDA1(kt + 2, a0) }
        CM1(w1, a1)
    }

    // epilogue: +b1, exact gelu, store bf16 h as [pair][col>>5][row][col&31]
    #pragma unroll
    for (int j = 0; j < 2; ++j) {
        const int col = n_base + 16 * j + lr;
        const float bias = b1[pair * 2048 + col];
        const size_t cbase = ((size_t)pair * 64 + (col >> 5)) * 128;
        const int cw = col & 31;
        #pragma unroll
        for (int i = 0; i < 4; ++i)
            #pragma unroll
            for (int r = 0; r < 4; ++r) {
                const int row = mh * 64 + 16 * i + lq * 4 + r;
                float x = acc[i][j][r] + bias;
                float g = 0.5f * x * (1.0f + erff(x * 0.70710678118654752f));
                hbuf[(cbase + row) * 32 + cw] = f2bf(g);
            }
    }
#undef LDA1
#undef LDW1
#undef CM1
}

// ---------------------------------------------------------------- pass 2
// 512 blocks: 64 pairs x 8 n-blocks of 64 over D=512.
// Wave tile 64m x 32n, K=2048 (64 steps). No LDS/barriers in the loop.
__global__ __launch_bounds__(256, 2) void k_gemm2(
    const unsigned short* __restrict__ hbuf, const float* __restrict__ W2,
    const float* __restrict__ b2, const float* __restrict__ tgt,
    float* __restrict__ partials)
{
    __shared__ float red[4];

    const int bi = blockIdx.x;
    const int xcd = bi & 7, slot = bi >> 3;       // slot 0..63
    const int pair = xcd * 8 + (slot >> 3);
    const int nb = slot & 7;
    const int a = pair >> 3;
    const int t = threadIdx.x;
    const int w = t >> 6, l = t & 63;
    const int lr = l & 15, lq = l >> 4;
    const int mh = w & 1, ns = w >> 1;
    const int n_base = nb * 64 + ns * 32;

    const float* W2p = W2 + (size_t)pair * (2048 * 512) + n_base + lr;
    // hbuf: [pair][kt][row][32]; frag i row = mh*64+16i+lr, k-part lq*8
    const unsigned short* Ap = hbuf + (size_t)pair * 262144
                             + (size_t)(mh * 64 + lr) * 32 + lq * 8;

    ushortx8 a0[4], a1[4];
    float w0[2][8], w1[2][8];

#define LDA2(KT, S)                                                            \
    {                                                                          \
        _Pragma("unroll")                                                      \
        for (int i = 0; i < 4; ++i)                                            \
            S[i] = *(const ushortx8*)(Ap + (size_t)(KT) * 4096 + i * 512);     \
    }
#define LDW2(KT, S)                                                            \
    {                                                                          \
        _Pragma("unroll")                                                      \
        for (int j = 0; j < 2; ++j)                                            \
            _Pragma("unroll")                                                  \
            for (int jj = 0; jj < 8; ++jj)                                     \
                S[j][jj] = __builtin_nontemporal_load(                         \
                    W2p + 16 * j + (size_t)((KT) * 32 + lq * 8 + jj) * 512);   \
    }
#define CM2(WS, AS)                                                            \
    {                                                                          \
        bf16x8 wf[2];                                                          \
        _Pragma("unroll")                                                      \
        for (int j = 0; j < 2; ++j) {                                          \
            ushortx8 v;                                                        \
            _Pragma("unroll")                                                  \
            for (int e = 0; e < 8; ++e) v[e] = f2bf(WS[j][e]);                 \
            wf[j] = __builtin_bit_cast(bf16x8, v);                             \
        }                                                                      \
        __builtin_amdgcn_s_setprio(1);                                         \
        _Pragma("unroll")                                                      \
        for (int i = 0; i < 4; ++i)                                            \
            _Pragma("unroll")                                                  \
            for (int j = 0; j < 2; ++j)                                        \
                acc[i][j] = __builtin_amdgcn_mfma_f32_16x16x32_bf16(           \
                    __builtin_bit_cast(bf16x8, AS[i]), wf[j], acc[i][j],       \
                    0, 0, 0);                                                  \
        __builtin_amdgcn_s_setprio(0);                                         \
    }

    floatx4 acc[4][2];
    const floatx4 zero = {0.f, 0.f, 0.f, 0.f};
    #pragma unroll
    for (int i = 0; i < 4; ++i)
        #pragma unroll
        for (int j = 0; j < 2; ++j) acc[i][j] = zero;

    LDW2(0, w0) LDA2(0, a0)
    #pragma unroll 1
    for (int kt = 0; kt < 64; kt += 2) {
        LDW2(kt + 1, w1) LDA2(kt + 1, a1)
        CM2(w0, a0)
        if (kt + 2 < 64) { LDW2(kt + 2, w0) LDA2(kt + 2, a0) }
        CM2(w1, a1)
    }

    // epilogue: squared-error accumulation
    float lsum = 0.f;
    #pragma unroll
    for (int j = 0; j < 2; ++j) {
        const int col = n_base + 16 * j + lr;
        const float bias = b2[pair * 512 + col];
        #pragma unroll
        for (int i = 0; i < 4; ++i)
            #pragma unroll
            for (int r = 0; r < 4; ++r) {
                const int row = mh * 64 + 16 * i + lq * 4 + r;
                float e = acc[i][j][r] + bias - tgt[((size_t)row * 8 + a) * 512 + col];
                lsum += e * e;
            }
    }
    #pragma unroll
    for (int off = 32; off > 0; off >>= 1) lsum += __shfl_down(lsum, off, 64);
    if (l == 0) red[w] = lsum;
    __syncthreads();
    if (t == 0) partials[bi] = red[0] + red[1] + red[2] + red[3];
#undef LDA2
#undef LDW2
#undef CM2
}

// ---------------------------------------------------------------- pass 3
__global__ void k_reduce(const float* __restrict__ partials, float* __restrict__ out)
{
    const int t = threadIdx.x;   // 512 threads
    float v = partials[t];
    #pragma unroll
    for (int off = 32; off > 0; off >>= 1) v += __shfl_down(v, off, 64);
    __shared__ float red[8];
    if ((t & 63) == 0) red[t >> 6] = v;
    __syncthreads();
    if (t == 0) {
        float s = 0.f;
        #pragma unroll
        for (int i = 0; i < 8; ++i) s += red[i];
        out[0] = s * (1.0f / 524288.0f); // /(B*D)/E
    }
}

extern "C" void kernel_launch(void* const* d_in, const int* in_sizes, int n_in,
                              void* d_out, int out_size, void* d_ws, size_t ws_size,
                              hipStream_t stream) {
    const float* feat = (const float*)d_in[0];
    const float* tgt  = (const float*)d_in[1];
    const float* W1   = (const float*)d_in[2];
    const float* b1   = (const float*)d_in[3];
    const float* W2   = (const float*)d_in[4];
    const float* b2   = (const float*)d_in[5];

    unsigned short* hbuf   = (unsigned short*)d_ws;                      // 32 MiB
    unsigned short* featbf = (unsigned short*)((char*)d_ws + 33554432);  // 1 MiB
    float* partials = (float*)((char*)d_ws + 33554432 + 1048576);        // 512 f
    float* out = (float*)d_out;

    k_prep <<<dim3(512),  dim3(256), 0, stream>>>(feat, featbf);
    k_gemm1<<<dim3(2048), dim3(256), 0, stream>>>(featbf, W1, b1, hbuf);
    k_gemm2<<<dim3(512),  dim3(256), 0, stream>>>(hbuf, W2, b2, tgt, partials);
    k_reduce<<<dim3(1),   dim3(512), 0, stream>>>(partials, out);
}